// Round 17
// baseline (120.385 us; speedup 1.0000x reference)
//
#include <hip/hip_runtime.h>
#include <hip/hip_bf16.h>

#define B_TOT 16384
#define C_CH  64
#define F_IN  128
#define H_HID 128
#define CG    2            // channels per block (1KB contiguous per row-chunk)
#define TROWS 16           // batch rows per tile
#define NSUB  32           // tiles per block -> 512 rows
#define ROWS  (NSUB * TROWS)

using f32x4  = __attribute__((ext_vector_type(4))) float;
using bf16x8 = __attribute__((ext_vector_type(8))) short;

__device__ inline unsigned pack2(float a, float b) {
    unsigned short lo = __builtin_bit_cast(unsigned short, __float2bfloat16(a));
    unsigned short hi = __builtin_bit_cast(unsigned short, __float2bfloat16(b));
    return (unsigned)lo | ((unsigned)hi << 16);
}

// async global->LDS, 16B/lane; LDS dest = wave-uniform base + lane*16 (HW rule)
__device__ inline void gld_lds16(const float* g, float* l) {
    __builtin_amdgcn_global_load_lds(
        (const __attribute__((address_space(1))) void*)g,
        (__attribute__((address_space(3))) void*)l, 16, 0, 0);
}

// Stage tile: 16 rows x 1KB (2 adjacent channels, contiguous). One instr per
// row = 64 lanes x 16B = the whole 1KB chunk. 4 waves x 4 rows. Source-side
// XOR swizzle (lane ^ (r&7)) so consume-side ds_read_b128 is bank-balanced.
// LDS: float off = r*256 + lane*4 holds global unit lane^sw of row-chunk r.
__device__ inline void issue_tile(const float* __restrict__ X, size_t base0,
                                  int wave, int lane, float* buf) {
    #pragma unroll
    for (int q = 0; q < 4; ++q) {
        const int r = wave * 4 + q;
        const float* rowp = X + base0 + (size_t)r * (C_CH * F_IN);
        const int sw = r & 7;
        gld_lds16(rowp + ((lane ^ sw) << 2), buf + r * 256);
    }
    asm volatile("" ::: "memory");   // pin vm-op program order (exact ledger)
}

// One round: counted vmcnt (exact ledger, never 0 mid-loop) + 4-wave barrier,
// 16 MFMA with W(regs) as A, X(LDS) as B => batch row lane-local; epilogue =
// in-lane relu-dot + 2 shuffles. b1 rides as MFMA C-init.
template<int N>
__device__ inline float compute_round(const float* __restrict__ xb,
                                      const bf16x8 (&wf)[4][4],
                                      const f32x4 (&w2c)[4],
                                      const f32x4 (&b1c)[4],
                                      int l15, int lg, int ch)
{
    asm volatile("s_waitcnt vmcnt(%0)" :: "i"(N) : "memory");
    __builtin_amdgcn_s_barrier();
    asm volatile("" ::: "memory");

    f32x4 acc[4];
    #pragma unroll
    for (int nf = 0; nf < 4; ++nf) acc[nf] = b1c[nf];

    const int sw = l15 & 7;
    const int rb = l15 * 256;
    #pragma unroll
    for (int ks = 0; ks < 4; ++ks) {
        const int u = ch * 32 + ks * 8 + lg * 2;
        float4 r0 = *reinterpret_cast<const float4*>(xb + rb + ((u ^ sw) << 2));
        float4 r1 = *reinterpret_cast<const float4*>(xb + rb + (((u + 1) ^ sw) << 2));
        uint4 px;
        px.x = pack2(r0.x, r0.y);
        px.y = pack2(r0.z, r0.w);
        px.z = pack2(r1.x, r1.y);
        px.w = pack2(r1.z, r1.w);
        bf16x8 xfrag = __builtin_bit_cast(bf16x8, px);
        #pragma unroll
        for (int nf = 0; nf < 4; ++nf)
            acc[nf] = __builtin_amdgcn_mfma_f32_16x16x32_bf16(
                wf[nf][ks], xfrag, acc[nf], 0, 0, 0);
    }

    float val = 0.f;
    #pragma unroll
    for (int nf = 0; nf < 4; ++nf)
        #pragma unroll
        for (int j = 0; j < 4; ++j)
            val += fmaxf(acc[nf][j], 0.f) * w2c[nf][j];
    val += __shfl_xor(val, 16, 64);   // sum the 4 lg-groups (h quarters)
    val += __shfl_xor(val, 32, 64);
    return val;
}

// 4-wave block, 48KB LDS -> 3 blocks/CU (3 independent barrier domains per CU;
// one block's barrier stall is backfilled by another block's compute).
// (256,3) caps VGPR at 168; natural need ~140 -> fits with slack (r6's spill
// was a ~175-need/168-cap collision).
__global__ __launch_bounds__(256, 3)
void fused_mlp_kernel(const float* __restrict__ X,
                      const float* __restrict__ W1,
                      const float* __restrict__ b1,
                      const float* __restrict__ W2,
                      const float* __restrict__ b2,
                      float* __restrict__ out)
{
    __shared__ alignas(16) float Xs[3 * TROWS * 256];   // 3 bufs x 16KB = 48KB

    const int t    = threadIdx.x;
    const int lane = t & 63;
    const int wave = t >> 6;            // 4 waves: role = (ch, h-half)
    const int l15  = lane & 15;
    const int lg   = lane >> 4;
    const int ch   = wave & 1;
    const int hh   = wave >> 1;

    const int c0 = blockIdx.x * CG;
    const int c  = c0 + ch;
    const int m0 = blockIdx.y * ROWS;

    float* bu0 = Xs;
    float* bu1 = Xs + TROWS * 256;
    float* bu2 = Xs + 2 * TROWS * 256;

    // prefill 2 tiles (depth-2; r12 showed depth-3 adds nothing); their HBM
    // latency hides under the W-register staging below
    const size_t cbase = ((size_t)m0 * C_CH + c0) * F_IN;
    const size_t tstep = (size_t)TROWS * C_CH * F_IN;
    issue_tile(X, cbase, wave, lane, bu0);
    issue_tile(X, cbase + tstep, wave, lane, bu1);

    // ---- W1 fragments -> registers (64 VGPR): wave owns (channel, h-half) ----
    bf16x8 wf[4][4];
    {
        const float* wb = W1 + (size_t)c * F_IN * H_HID + hh * 64 + l15;
        #pragma unroll
        for (int nf = 0; nf < 4; ++nf)
            #pragma unroll
            for (int ks = 0; ks < 4; ++ks) {
                const int f0 = ks * 32 + lg * 8;
                float v[8];
                #pragma unroll
                for (int e = 0; e < 8; ++e)
                    v[e] = wb[(size_t)(f0 + e) * H_HID + nf * 16];
                uint4 p;
                p.x = pack2(v[0], v[1]);
                p.y = pack2(v[2], v[3]);
                p.z = pack2(v[4], v[5]);
                p.w = pack2(v[6], v[7]);
                wf[nf][ks] = __builtin_bit_cast(bf16x8, p);
            }
    }
    f32x4 w2c[4], b1c[4];
    #pragma unroll
    for (int nf = 0; nf < 4; ++nf) {
        const int ho = c * H_HID + hh * 64 + nf * 16 + lg * 4;
        w2c[nf] = *reinterpret_cast<const f32x4*>(W2 + ho);
        b1c[nf] = *reinterpret_cast<const f32x4*>(b1 + ho);
    }
    const float b2c = (hh == 0) ? b2[c] : 0.f;   // b2[c] added once per channel

    // ---- vmcnt ledger (per wave, order pinned by fences) ----
    // prefill [L0][L1]; round sc: [wait][barrier][compute][L_{sc+2}][A_sc].
    // younger-than-L_sc at wait(sc): sc=0: L1=4; sc=1: L2+A0=5;
    // sc in 2..30: A_{sc-2}+L_{sc+1}+A_{sc-1}=6; sc=31: A29+A30=2.
    #define DO_ROUND(NWAIT, SC, ISSUE)                                          \
        {                                                                       \
            float val = compute_round<NWAIT>(bu0, wf, w2c, b1c, l15, lg, ch);   \
            if (ISSUE)                                                          \
                issue_tile(X, cbase + (size_t)((SC) + 2) * tstep, wave, lane, bu2); \
            if (lane < 16) atomicAdd(&out[m0 + (SC) * TROWS + lane], val + b2c); \
            asm volatile("" ::: "memory");                                      \
            float* tmp = bu0; bu0 = bu1; bu1 = bu2; bu2 = tmp;                  \
        }

    DO_ROUND(4, 0, true)
    DO_ROUND(5, 1, true)
    #pragma unroll 1
    for (int sc = 2; sc <= 30; ++sc)
        DO_ROUND(6, sc, (sc + 2 < NSUB))
    DO_ROUND(2, 31, false)
    #undef DO_ROUND
}

extern "C" void kernel_launch(void* const* d_in, const int* in_sizes, int n_in,
                              void* d_out, int out_size, void* d_ws, size_t ws_size,
                              hipStream_t stream) {
    const float* X  = (const float*)d_in[0];   // [B, C, F]
    const float* W1 = (const float*)d_in[1];   // [C, F, H]
    const float* b1 = (const float*)d_in[2];   // [C, H]
    const float* W2 = (const float*)d_in[3];   // [C, H]
    const float* b2 = (const float*)d_in[4];   // [C]
    float* out = (float*)d_out;                // [B]

    // atomics accumulate into out -> must zero it every call (d_out is poisoned)
    hipMemsetAsync(out, 0, (size_t)out_size * sizeof(float), stream);

    dim3 grid(C_CH / CG, B_TOT / ROWS);   // (32, 32) = 1024 blocks, channel-major
    fused_mlp_kernel<<<grid, dim3(256), 0, stream>>>(X, W1, b1, W2, b2, out);
}

// Round 18
// 106.733 us; speedup vs baseline: 1.1279x; 1.1279x over previous
//
#include <hip/hip_runtime.h>
#include <hip/hip_bf16.h>

#define B_TOT 16384
#define C_CH  64
#define F_IN  128
#define H_HID 128
#define CG    4            // channels per block (2KB contiguous per row-chunk)
#define TROWS 16           // batch rows per tile
#define NSUB  64           // tiles per block -> 1024 rows
#define ROWS  (NSUB * TROWS)
#define NCG   (C_CH / CG)  // 16 channel-group slices

using f32x4  = __attribute__((ext_vector_type(4))) float;
using bf16x8 = __attribute__((ext_vector_type(8))) short;

__device__ inline unsigned pack2(float a, float b) {
    unsigned short lo = __builtin_bit_cast(unsigned short, __float2bfloat16(a));
    unsigned short hi = __builtin_bit_cast(unsigned short, __float2bfloat16(b));
    return (unsigned)lo | ((unsigned)hi << 16);
}

// async global->LDS, 16B/lane; LDS dest = wave-uniform base + lane*16 (HW rule)
__device__ inline void gld_lds16(const float* g, float* l) {
    __builtin_amdgcn_global_load_lds(
        (const __attribute__((address_space(1))) void*)g,
        (__attribute__((address_space(3))) void*)l, 16, 0, 0);
}

// Stage tile: 16 rows x 2KB (4 adjacent channels = contiguous span; ~HBM page).
// Each instr reads a fully CONTIGUOUS 1KB. Source-side XOR swizzle
// (lane ^ (row&7)) so consume-side ds_read_b128 is bank-balanced.
// LDS: float off = r*512 + h*256 + lane*4 holds global unit lane^sw.
__device__ inline void issue_tile(const float* __restrict__ X, size_t base0,
                                  int wave, int lane, float* buf) {
    #pragma unroll
    for (int q = 0; q < 2; ++q) {
        const int r = wave * 2 + q;                    // 8 waves x 2 rows = 16
        const float* rowp = X + base0 + (size_t)r * (C_CH * F_IN);
        const int sw = r & 7;
        #pragma unroll
        for (int h = 0; h < 2; ++h)
            gld_lds16(rowp + h * 256 + ((lane ^ sw) << 2),
                      buf + r * 512 + h * 256);
    }
    asm volatile("" ::: "memory");   // pin vm-op program order (exact ledger)
}

// One round: counted vmcnt (exact ledger, NEVER includes atomics), barrier,
// 16 MFMA with W(regs) as A, X(LDS) as B => batch row lane-local; epilogue =
// in-lane relu-dot + 2 shuffles. b1 rides as MFMA C-init.
template<int N>
__device__ inline float compute_round(const float* __restrict__ xb,
                                      const bf16x8 (&wf)[4][4],
                                      const f32x4 (&w2c)[4],
                                      const f32x4 (&b1c)[4],
                                      int l15, int lg, int ch)
{
    asm volatile("s_waitcnt vmcnt(%0)" :: "i"(N) : "memory");
    __builtin_amdgcn_s_barrier();
    asm volatile("" ::: "memory");

    f32x4 acc[4];
    #pragma unroll
    for (int nf = 0; nf < 4; ++nf) acc[nf] = b1c[nf];

    const int sw = l15 & 7;
    const int rb = l15 * 512 + (ch >> 1) * 256;
    #pragma unroll
    for (int ks = 0; ks < 4; ++ks) {
        const int u = (ch & 1) * 32 + ks * 8 + lg * 2;
        float4 r0 = *reinterpret_cast<const float4*>(xb + rb + ((u ^ sw) << 2));
        float4 r1 = *reinterpret_cast<const float4*>(xb + rb + (((u + 1) ^ sw) << 2));
        uint4 px;
        px.x = pack2(r0.x, r0.y);
        px.y = pack2(r0.z, r0.w);
        px.z = pack2(r1.x, r1.y);
        px.w = pack2(r1.z, r1.w);
        bf16x8 xfrag = __builtin_bit_cast(bf16x8, px);
        #pragma unroll
        for (int nf = 0; nf < 4; ++nf)
            acc[nf] = __builtin_amdgcn_mfma_f32_16x16x32_bf16(
                wf[nf][ks], xfrag, acc[nf], 0, 0, 0);
    }

    float val = 0.f;
    #pragma unroll
    for (int nf = 0; nf < 4; ++nf)
        #pragma unroll
        for (int j = 0; j < 4; ++j)
            val += fmaxf(acc[nf][j], 0.f) * w2c[nf][j];
    val += __shfl_xor(val, 16, 64);   // sum the 4 lg-groups (h quarters)
    val += __shfl_xor(val, 32, 64);
    return val;
}

__global__ __launch_bounds__(512, 2)
void fused_mlp_kernel(const float* __restrict__ X,
                      const float* __restrict__ W1,
                      const float* __restrict__ b1,
                      const float* __restrict__ W2,
                      const float* __restrict__ b2,
                      float* __restrict__ dest,   // out (sstride=0) or partials
                      int sstride)                // B_TOT when slicing per cg
{
    __shared__ alignas(16) float Xs[3 * TROWS * 512];   // 3 bufs x 32KB = 96KB

    const int t    = threadIdx.x;
    const int lane = t & 63;
    const int wave = t >> 6;            // 8 waves: role = (ch, h-half)
    const int l15  = lane & 15;
    const int lg   = lane >> 4;
    const int ch   = wave & 3;
    const int hh   = wave >> 2;

    const int c0 = blockIdx.x * CG;
    const int c  = c0 + ch;
    const int m0 = blockIdx.y * ROWS;
    // private slice: same-line atomics contended only by this block's 8 waves
    // (XCD-local L2 line; no cross-XCD ping-pong)
    const int dbase = blockIdx.x * sstride + m0;

    float* bu0 = Xs;
    float* bu1 = Xs + TROWS * 512;
    float* bu2 = Xs + 2 * TROWS * 512;

    // prefill 2 tiles (depth-2; r12 showed depth-3 is null); HBM latency
    // hides under W-register staging below
    const size_t cbase = ((size_t)m0 * C_CH + c0) * F_IN;
    const size_t tstep = (size_t)TROWS * C_CH * F_IN;
    issue_tile(X, cbase, wave, lane, bu0);
    issue_tile(X, cbase + tstep, wave, lane, bu1);

    // ---- W1 fragments -> registers (64 VGPR): wave owns (channel, h-half) ----
    bf16x8 wf[4][4];
    {
        const float* wb = W1 + (size_t)c * F_IN * H_HID + hh * 64 + l15;
        #pragma unroll
        for (int nf = 0; nf < 4; ++nf)
            #pragma unroll
            for (int ks = 0; ks < 4; ++ks) {
                const int f0 = ks * 32 + lg * 8;
                float v[8];
                #pragma unroll
                for (int e = 0; e < 8; ++e)
                    v[e] = wb[(size_t)(f0 + e) * H_HID + nf * 16];
                uint4 p;
                p.x = pack2(v[0], v[1]);
                p.y = pack2(v[2], v[3]);
                p.z = pack2(v[4], v[5]);
                p.w = pack2(v[6], v[7]);
                wf[nf][ks] = __builtin_bit_cast(bf16x8, p);
            }
    }
    f32x4 w2c[4], b1c[4];
    #pragma unroll
    for (int nf = 0; nf < 4; ++nf) {
        const int ho = c * H_HID + hh * 64 + nf * 16 + lg * 4;
        w2c[nf] = *reinterpret_cast<const f32x4*>(W2 + ho);
        b1c[nf] = *reinterpret_cast<const f32x4*>(b1 + ho);
    }
    const float b2c = (hh == 0) ? b2[c] : 0.f;   // b2[c] added once per channel

    // ---- vmcnt ledger (per wave, order pinned; atomics NEVER waited on) ----
    // prefill [L0][L1]; round sc: [wait][barrier][compute][L_{sc+2}][A_sc].
    // younger-than-L_sc at wait(sc): sc=0: L1=4; sc=1: L2+A0=5;
    // sc 2..62: A_{sc-2}+L_{sc+1}(4)+A_{sc-1}=6 (r9 used 5 -> waited on an
    // atomic every round); sc=63: A61+A62=2.
    #define DO_ROUND(NWAIT, SC, ISSUE)                                          \
        {                                                                       \
            float val = compute_round<NWAIT>(bu0, wf, w2c, b1c, l15, lg, ch);   \
            if (ISSUE)                                                          \
                issue_tile(X, cbase + (size_t)((SC) + 2) * tstep, wave, lane, bu2); \
            if (lane < 16) atomicAdd(&dest[dbase + (SC) * TROWS + lane], val + b2c); \
            asm volatile("" ::: "memory");                                      \
            float* tmp = bu0; bu0 = bu1; bu1 = bu2; bu2 = tmp;                  \
        }

    DO_ROUND(4, 0, true)
    DO_ROUND(5, 1, true)
    #pragma unroll 1
    for (int sc = 2; sc <= 62; ++sc)
        DO_ROUND(6, sc, (sc + 2 < NSUB))
    DO_ROUND(2, 63, false)
    #undef DO_ROUND
}

// out[r] = sum over the 16 cg slices (plain stores -> no memset of out needed)
__global__ __launch_bounds__(256)
void reduce_kernel(const float* __restrict__ part, float* __restrict__ out)
{
    const int idx = blockIdx.x * blockDim.x + threadIdx.x;   // float4 index
    if (idx < B_TOT / 4) {
        f32x4 acc = f32x4{0.f, 0.f, 0.f, 0.f};
        #pragma unroll
        for (int s = 0; s < NCG; ++s)
            acc += *reinterpret_cast<const f32x4*>(part + (size_t)s * B_TOT + idx * 4);
        *reinterpret_cast<f32x4*>(out + idx * 4) = acc;
    }
}

extern "C" void kernel_launch(void* const* d_in, const int* in_sizes, int n_in,
                              void* d_out, int out_size, void* d_ws, size_t ws_size,
                              hipStream_t stream) {
    const float* X  = (const float*)d_in[0];   // [B, C, F]
    const float* W1 = (const float*)d_in[1];   // [C, F, H]
    const float* b1 = (const float*)d_in[2];   // [C, H]
    const float* W2 = (const float*)d_in[3];   // [C, H]
    const float* b2 = (const float*)d_in[4];   // [C]
    float* out = (float*)d_out;                // [B]

    const size_t part_bytes = (size_t)NCG * B_TOT * sizeof(float);  // 1 MB
    dim3 grid(C_CH / CG, B_TOT / ROWS);        // (16, 16) = 256 blocks = 1/CU

    if (ws_size >= part_bytes) {
        // two-pass: per-cg partial slices (no cross-XCD same-line atomics)
        float* part = (float*)d_ws;
        hipMemsetAsync(part, 0, part_bytes, stream);   // atomics accumulate
        fused_mlp_kernel<<<grid, dim3(512), 0, stream>>>(X, W1, b1, W2, b2,
                                                         part, B_TOT);
        reduce_kernel<<<dim3(B_TOT / 4 / 256), dim3(256), 0, stream>>>(part, out);
    } else {
        // fallback = r9 behavior (direct atomics into out) + corrected ledger
        hipMemsetAsync(out, 0, (size_t)out_size * sizeof(float), stream);
        fused_mlp_kernel<<<grid, dim3(512), 0, stream>>>(X, W1, b1, W2, b2,
                                                         out, 0);
    }
}